// Round 4
// baseline (445.614 us; speedup 1.0000x reference)
//
#include <hip/hip_runtime.h>
#include <hip/hip_bf16.h>

// GCN inference: conv1(128->16)+ReLU -> conv2(16->16) -> linear(16->40) -> log_softmax
// R11 post-mortem: LDS-staged partition worked (430us; partition left top-5).
// k_bucketsort top again (81us, HBM 19%, VALU 3%, Occ 45%) -- width-capped at
// 391 blocks (1.53/CU). R12: split the fine sort into wide kernels:
//   k_bsA  (391*4 blocks): per-quarter LDS histogram -> global atomic cnt/deg
//   k_bsOffs (391 blocks): bucket scan -> offs, dinv=rsqrt(deg)
//   k_bsB  (391*2 blocks): both-ends scatter -- (k,0) forward from offs[n],
//          (k,1) backward from offs[n+1]; no cross-slice bases needed.
// cnt overlays dead histc region (= edata head): read last by bsOffs, dead
// before bsB writes edata. deg accumulates in dinv's slot (init 1.0 for the
// self-loop), rsqrt'd in place by bsOffs.

#define N_NODES 100000
#define N_EDGES 6400000
#define IN_DIM  128
#define HID     16
#define NCLS    40

#define K_BKT    391         // buckets = col>>8, 256 nodes each (last: 160)
#define BKT_SH   8
#define BKT_NB   256         // nodes per bucket
#define BKT_MASK 255
#define B_PART   1000        // histogram/partition blocks
#define CHUNK    6400        // edges per partition block (fits LDS staging)

// ---- tier-1 workspace layout (bytes) ----
#define OFF_CB    0          // int[392] bucket bases (exclusive scan of totals)
#define OFF_TOT   1600       // int[391] bucket totals
#define OFF_DINV  3200       // float[N]: deg accum (init 1.0), then rsqrt in place
#define OFF_OFFS  403200     // int[N+1]
#define OFF_EBUF1 803328     // int2[E] bucket-major edges (dead after bsB)
#define OFF_EDATA 52003328   // int2[E] final CSR (row, w)
#define OFF_HIST   OFF_EDATA               // int[1000*391] counts (dead after partition)
#define OFF_HISTEX (OFF_EDATA + 1568000)   // int[1000*391] exclusive scans (dead after partition)
#define OFF_CNT    OFF_EDATA               // int[N] per-node counts (init2..bsOffs window)
#define WS_T1_NEED 103600000
// h1/hb overlay the dead ebuf1 region:
#define OFF_H1    OFF_EBUF1              // float[N*16]
#define OFF_HB    (OFF_EBUF1 + 6400000)  // float[N*16]

// ---- tier-2 workspace layout (R5 atomic-CSR path) ----
#define T2_DINV  0
#define T2_CNT   400128
#define T2_OFFS  800256
#define T2_EDATA 1200384
#define T2_H1    52400384
#define T2_HB    58800384
#define T2_BSUM  65200384
#define WS_T2_NEED 65210000

// ---- tier-3 fallback layout ----
#define OFF3_DEG 0
#define OFF3_H1  400128
#define OFF3_HB  6800384

// =================== tier-1: deterministic CSR build ===================

__global__ __launch_bounds__(1024) void k_hist(const int* col, int* histcnt) {
    __shared__ int h[K_BKT];
    int t = threadIdx.x;
    if (t < K_BKT) h[t] = 0;
    __syncthreads();
    int b = blockIdx.x;
    int end = (b + 1) * CHUNK;
    int e = b * CHUNK + t;
    for (; e + 3072 < end; e += 4096) {
        int c0 = col[e];
        int c1 = col[e + 1024];
        int c2 = col[e + 2048];
        int c3 = col[e + 3072];
        atomicAdd(&h[c0 >> BKT_SH], 1);               // LDS int atomic: fast path
        atomicAdd(&h[c1 >> BKT_SH], 1);
        atomicAdd(&h[c2 >> BKT_SH], 1);
        atomicAdd(&h[c3 >> BKT_SH], 1);
    }
    for (; e < end; e += 1024)
        atomicAdd(&h[col[e] >> BKT_SH], 1);
    __syncthreads();
    if (t < K_BKT) histcnt[b * K_BKT + t] = h[t];
}

// one block per bucket k: exclusive-scan histcnt[.][k] over the 1000 blocks
// into histex (histcnt preserved -- partition needs local counts).
__global__ __launch_bounds__(1024) void k_colscan(const int* histcnt, int* histex, int* tot) {
    __shared__ int s[1024];
    int t = threadIdx.x;
    int k = blockIdx.x;
    int v = (t < B_PART) ? histcnt[t * K_BKT + k] : 0;
    s[t] = v;
    __syncthreads();
    for (int o = 1; o < 1024; o <<= 1) {
        int a = (t >= o) ? s[t - o] : 0;
        __syncthreads();
        s[t] += a;
        __syncthreads();
    }
    if (t < B_PART) histex[t * K_BKT + k] = s[t] - v;  // exclusive
    if (t == 0) tot[k] = s[B_PART - 1];                // inclusive total
}

__global__ __launch_bounds__(512) void k_basescan(const int* tot, int* cbase) {
    __shared__ int s[512];
    int t = threadIdx.x;
    int v = (t < K_BKT) ? tot[t] : 0;
    s[t] = v;
    __syncthreads();
    for (int o = 1; o < 512; o <<= 1) {
        int a = (t >= o) ? s[t - o] : 0;
        __syncthreads();
        s[t] += a;
        __syncthreads();
    }
    if (t < K_BKT) cbase[t] = s[t] - v;               // exclusive
    if (t == 0) cbase[K_BKT] = N_EDGES;
}

// LDS-staged partition: counting-sort the block's chunk in LDS, then write
// bucket-segments to global in slot order (coalesced runs).
// packed = row | (col_local<<17)
__global__ __launch_bounds__(1024) void k_partition(const int* row, const int* col,
                                                    const float* w, const int* histcnt,
                                                    const int* histex, const int* cbase,
                                                    int2* ebuf1) {
    __shared__ int2 led[CHUNK];          // 51.2KB staged edges (local sorted order)
    __shared__ int  sscan[1024];
    __shared__ int  lbase[K_BKT + 1];    // local exclusive offsets
    __shared__ int  gofs[K_BKT];         // global_base - local_base per bucket
    __shared__ int  cur[K_BKT];
    int t = threadIdx.x;
    int b = blockIdx.x;
    // local exclusive scan of this block's bucket counts
    int v = (t < K_BKT) ? histcnt[b * K_BKT + t] : 0;
    sscan[t] = v;
    __syncthreads();
    for (int o = 1; o < 1024; o <<= 1) {
        int a = (t >= o) ? sscan[t - o] : 0;
        __syncthreads();
        sscan[t] += a;
        __syncthreads();
    }
    if (t < K_BKT) {
        int ex = sscan[t] - v;
        lbase[t] = ex;
        cur[t] = ex;
        gofs[t] = cbase[t] + histex[b * K_BKT + t] - ex;
    }
    if (t == 0) lbase[K_BKT] = CHUNK;
    __syncthreads();
    // local scatter into LDS (2x unrolled; LDS store latency trivial)
    int end = (b + 1) * CHUNK;
    int e = b * CHUNK + t;
    for (; e + 1024 < end; e += 2048) {
        int c0 = col[e],  c1 = col[e + 1024];
        int r0 = row[e],  r1 = row[e + 1024];
        float w0 = w[e],  w1 = w[e + 1024];
        int p0 = atomicAdd(&cur[c0 >> BKT_SH], 1);
        int p1 = atomicAdd(&cur[c1 >> BKT_SH], 1);
        led[p0] = make_int2(r0 | ((c0 & BKT_MASK) << 17), __float_as_int(w0));
        led[p1] = make_int2(r1 | ((c1 & BKT_MASK) << 17), __float_as_int(w1));
    }
    for (; e < end; e += 1024) {
        int c = col[e];
        int p = atomicAdd(&cur[c >> BKT_SH], 1);
        led[p] = make_int2(row[e] | ((c & BKT_MASK) << 17), __float_as_int(w[e]));
    }
    __syncthreads();
    // write-out in slot order -> consecutive threads hit consecutive global
    // addresses within each bucket segment (coalesced runs, no atomic dep).
    for (int i = t; i < CHUNK; i += 1024) {
        int2 ed = led[i];
        int lo = 0, hi = K_BKT;          // find k: lbase[k] <= i < lbase[k+1]
        while (hi - lo > 1) {
            int mid = (lo + hi) >> 1;
            if (lbase[mid] <= i) lo = mid; else hi = mid;
        }
        ebuf1[gofs[lo] + i] = ed;
    }
}

// zero per-node counts, init deg to 1.0 (self loop weight)
__global__ __launch_bounds__(256) void k_init2(int* cnt, float* deg) {
    int i = blockIdx.x * 256 + threadIdx.x;
    if (i < N_NODES) { cnt[i] = 0; deg[i] = 1.0f; }
}

// fine count: 4 blocks per bucket, each histograms its quarter of the bucket's
// edge range in LDS, then flushes 256 global atomics (cnt) + 256 f32 atomics (deg).
__global__ __launch_bounds__(1024) void k_bsA(const int2* ebuf1, const int* cbase,
                                              int* cnt, float* deg) {
    __shared__ int   lcnt[BKT_NB];
    __shared__ float ldeg[BKT_NB];
    int t = threadIdx.x;
    int k = blockIdx.x >> 2;
    int q = blockIdx.x & 3;
    if (t < BKT_NB) { lcnt[t] = 0; ldeg[t] = 0.0f; }
    __syncthreads();
    int e0 = cbase[k], e1 = cbase[k + 1];
    int len = e1 - e0;
    int es = e0 + ((len * q) >> 2);
    int ee = e0 + ((len * (q + 1)) >> 2);
    int e = es + t;
    for (; e + 3072 < ee; e += 4096) {
        int2 v0 = ebuf1[e];
        int2 v1 = ebuf1[e + 1024];
        int2 v2 = ebuf1[e + 2048];
        int2 v3 = ebuf1[e + 3072];
        int a0 = v0.x >> 17, a1 = v1.x >> 17, a2 = v2.x >> 17, a3 = v3.x >> 17;
        atomicAdd(&lcnt[a0], 1); atomicAdd(&ldeg[a0], __int_as_float(v0.y));
        atomicAdd(&lcnt[a1], 1); atomicAdd(&ldeg[a1], __int_as_float(v1.y));
        atomicAdd(&lcnt[a2], 1); atomicAdd(&ldeg[a2], __int_as_float(v2.y));
        atomicAdd(&lcnt[a3], 1); atomicAdd(&ldeg[a3], __int_as_float(v3.y));
    }
    for (; e < ee; e += 1024) {
        int2 v = ebuf1[e];
        int cl = v.x >> 17;
        atomicAdd(&lcnt[cl], 1);
        atomicAdd(&ldeg[cl], __int_as_float(v.y));
    }
    __syncthreads();
    if (t < BKT_NB && lcnt[t] > 0) {
        int node = k * BKT_NB + t;
        atomicAdd(&cnt[node], lcnt[t]);              // global int atomic
        unsafeAtomicAdd(&deg[node], ldeg[t]);        // global f32 fire-and-forget
    }
}

// per-bucket scan of fine counts -> offs; dinv = rsqrt(deg) in place
__global__ __launch_bounds__(256) void k_bsOffs(const int* cnt, const int* cbase,
                                                int* offs, float* dinv) {
    __shared__ int sc[BKT_NB];
    int t = threadIdx.x;
    int k = blockIdx.x;
    int node = k * BKT_NB + t;
    int c = (node < N_NODES) ? cnt[node] : 0;
    sc[t] = c;
    __syncthreads();
    for (int o = 1; o < BKT_NB; o <<= 1) {
        int a = (t >= o) ? sc[t - o] : 0;
        __syncthreads();
        sc[t] += a;
        __syncthreads();
    }
    if (node < N_NODES) {
        offs[node] = cbase[k] + sc[t] - c;
        dinv[node] = rsqrtf(dinv[node]);
    }
    if (k == 0 && t == 0) offs[N_NODES] = N_EDGES;
}

// both-ends scatter: (k,0) forward from offs[node], (k,1) backward from
// offs[node+1]. Segments meet exactly; within-node order is irrelevant (sum).
__global__ __launch_bounds__(1024) void k_bsB(const int2* ebuf1, const int* cbase,
                                              const int* offs, int2* edata) {
    __shared__ int cur[BKT_NB];
    int t = threadIdx.x;
    int k = blockIdx.x >> 1;
    int s = blockIdx.x & 1;
    int e0 = cbase[k], e1 = cbase[k + 1];
    if (t < BKT_NB) {
        int node = k * BKT_NB + t;
        cur[t] = (node < N_NODES) ? offs[node + s] : 0;
    }
    __syncthreads();
    int mid = e0 + ((e1 - e0) >> 1);
    if (s == 0) {
        int e = e0 + t;
        for (; e + 3072 < mid; e += 4096) {
            int2 v0 = ebuf1[e];
            int2 v1 = ebuf1[e + 1024];
            int2 v2 = ebuf1[e + 2048];
            int2 v3 = ebuf1[e + 3072];
            int p0 = atomicAdd(&cur[v0.x >> 17], 1);
            int p1 = atomicAdd(&cur[v1.x >> 17], 1);
            int p2 = atomicAdd(&cur[v2.x >> 17], 1);
            int p3 = atomicAdd(&cur[v3.x >> 17], 1);
            edata[p0] = make_int2(v0.x & 131071, v0.y);
            edata[p1] = make_int2(v1.x & 131071, v1.y);
            edata[p2] = make_int2(v2.x & 131071, v2.y);
            edata[p3] = make_int2(v3.x & 131071, v3.y);
        }
        for (; e < mid; e += 1024) {
            int2 v = ebuf1[e];
            int p = atomicAdd(&cur[v.x >> 17], 1);
            edata[p] = make_int2(v.x & 131071, v.y);
        }
    } else {
        int e = mid + t;
        for (; e + 3072 < e1; e += 4096) {
            int2 v0 = ebuf1[e];
            int2 v1 = ebuf1[e + 1024];
            int2 v2 = ebuf1[e + 2048];
            int2 v3 = ebuf1[e + 3072];
            int p0 = atomicAdd(&cur[v0.x >> 17], -1) - 1;
            int p1 = atomicAdd(&cur[v1.x >> 17], -1) - 1;
            int p2 = atomicAdd(&cur[v2.x >> 17], -1) - 1;
            int p3 = atomicAdd(&cur[v3.x >> 17], -1) - 1;
            edata[p0] = make_int2(v0.x & 131071, v0.y);
            edata[p1] = make_int2(v1.x & 131071, v1.y);
            edata[p2] = make_int2(v2.x & 131071, v2.y);
            edata[p3] = make_int2(v3.x & 131071, v3.y);
        }
        for (; e < e1; e += 1024) {
            int2 v = ebuf1[e];
            int p = atomicAdd(&cur[v.x >> 17], -1) - 1;
            edata[p] = make_int2(v.x & 131071, v.y);
        }
    }
}

// =================== shared compute kernels ===================

// h1 = dinv[node] * (z @ W1); dinv=nullptr -> unscaled (tier-3)
__global__ __launch_bounds__(256) void k_gemm1(const float* z, const float* W1, float* h1,
                                               const float* dinv) {
    __shared__ float w1s[IN_DIM * HID];
    __shared__ float zs[64 * 132];
    int tid = threadIdx.x;
    for (int i = tid; i < IN_DIM * HID / 4; i += 256)
        ((float4*)w1s)[i] = ((const float4*)W1)[i];
    int nodeBase = blockIdx.x * 64;
    for (int i = tid; i < 64 * 32; i += 256) {
        int nl = i >> 5, kq = i & 31;
        int node = nodeBase + nl;
        float4 v = (node < N_NODES) ? ((const float4*)z)[node * 32 + kq]
                                    : make_float4(0.f, 0.f, 0.f, 0.f);
        *(float4*)&zs[nl * 132 + kq * 4] = v;
    }
    __syncthreads();
    int nl = tid >> 2;
    int jb = (tid & 3) * 4;
    int node = nodeBase + nl;
    float4 acc = make_float4(0.f, 0.f, 0.f, 0.f);
    for (int k = 0; k < IN_DIM; k++) {
        float s = zs[nl * 132 + k];
        float4 wv = *(const float4*)&w1s[k * HID + jb];
        acc.x += s * wv.x; acc.y += s * wv.y; acc.z += s * wv.z; acc.w += s * wv.w;
    }
    if (node < N_NODES) {
        float dv = dinv ? dinv[node] : 1.0f;
        acc.x *= dv; acc.y *= dv; acc.z *= dv; acc.w *= dv;
        ((float4*)h1)[node * 4 + (tid & 3)] = acc;
    }
}

// 8x-unrolled CSR edge aggregation: 8 independent edata loads + 8 independent
// gathers in flight per 16-lane group.
__device__ __forceinline__ float edge_agg(const float* __restrict__ h,
                                          const int2* __restrict__ edata,
                                          int e0, int e1, int lane, float acc) {
    int e = e0;
    for (; e + 8 <= e1; e += 8) {
        int2 d0 = edata[e];
        int2 d1 = edata[e + 1];
        int2 d2 = edata[e + 2];
        int2 d3 = edata[e + 3];
        int2 d4 = edata[e + 4];
        int2 d5 = edata[e + 5];
        int2 d6 = edata[e + 6];
        int2 d7 = edata[e + 7];
        float g0 = h[d0.x * HID + lane];
        float g1 = h[d1.x * HID + lane];
        float g2 = h[d2.x * HID + lane];
        float g3 = h[d3.x * HID + lane];
        float g4 = h[d4.x * HID + lane];
        float g5 = h[d5.x * HID + lane];
        float g6 = h[d6.x * HID + lane];
        float g7 = h[d7.x * HID + lane];
        acc += __int_as_float(d0.y) * g0;
        acc += __int_as_float(d1.y) * g1;
        acc += __int_as_float(d2.y) * g2;
        acc += __int_as_float(d3.y) * g3;
        acc += __int_as_float(d4.y) * g4;
        acc += __int_as_float(d5.y) * g5;
        acc += __int_as_float(d6.y) * g6;
        acc += __int_as_float(d7.y) * g7;
    }
    for (; e < e1; e++) {
        int2 ed = edata[e];
        acc += __int_as_float(ed.y) * h[ed.x * HID + lane];
    }
    return acc;
}

// conv1 aggregate (+b1, ReLU), fused h2 = x1 @ W2; hb = dinv * h2
__global__ __launch_bounds__(256) void k_agg1(const float* h1, const float* dinv,
                                              const int* offs, const int2* edata,
                                              const float* b1, const float* W2, float* hb) {
    __shared__ float w2s[HID * HID];
    int tid = threadIdx.x;
    if (tid < HID * HID) w2s[tid] = W2[tid];
    __syncthreads();
    int lane = tid & 15;
    int node = blockIdx.x * 16 + (tid >> 4);
    int e0 = offs[node], e1 = offs[node + 1];
    float acc = edge_agg(h1, edata, e0, e1, lane, h1[node * HID + lane]);
    float d = dinv[node];
    acc = d * acc + b1[lane];
    acc = fmaxf(acc, 0.0f);
    int base = tid & 48;
    float h2 = 0.0f;
    for (int k = 0; k < HID; k++) {
        float v = __shfl(acc, base + k, 64);
        h2 += v * w2s[k * HID + lane];
    }
    hb[node * HID + lane] = d * h2;
}

// conv2 aggregate (+b2), classifier (16->40) + log_softmax
__global__ __launch_bounds__(256) void k_agg2(const float* hb, const float* dinv,
                                              const int* offs, const int2* edata,
                                              const float* b2, const float* Wc,
                                              const float* bc, float* out) {
    __shared__ float wcs[HID * NCLS];
    __shared__ float bcs[NCLS];
    int tid = threadIdx.x;
    for (int i = tid; i < HID * NCLS; i += 256) wcs[i] = Wc[i];
    if (tid < NCLS) bcs[tid] = bc[tid];
    __syncthreads();
    int lane = tid & 15;
    int node = blockIdx.x * 16 + (tid >> 4);
    int e0 = offs[node], e1 = offs[node + 1];
    float acc = edge_agg(hb, edata, e0, e1, lane, hb[node * HID + lane]);
    acc = dinv[node] * acc + b2[lane];
    float l0 = bcs[lane];
    float l1 = bcs[lane + 16];
    float l2 = (lane < 8) ? bcs[lane + 32] : 0.0f;
    int base = tid & 48;
    for (int k = 0; k < HID; k++) {
        float v = __shfl(acc, base + k, 64);
        l0 += v * wcs[k * NCLS + lane];
        l1 += v * wcs[k * NCLS + lane + 16];
        if (lane < 8) l2 += v * wcs[k * NCLS + lane + 32];
    }
    float m = fmaxf(l0, l1);
    if (lane < 8) m = fmaxf(m, l2);
    for (int o = 1; o < 16; o <<= 1) m = fmaxf(m, __shfl_xor(m, o, 64));
    float s = expf(l0 - m) + expf(l1 - m) + ((lane < 8) ? expf(l2 - m) : 0.0f);
    for (int o = 1; o < 16; o <<= 1) s += __shfl_xor(s, o, 64);
    float ls = logf(s) + m;
    out[node * NCLS + lane] = l0 - ls;
    out[node * NCLS + lane + 16] = l1 - ls;
    if (lane < 8) out[node * NCLS + lane + 32] = l2 - ls;
}

// =================== tier-2: R5 atomic-CSR build ===================

__global__ __launch_bounds__(256) void k_init(int* cnt) {
    int i = blockIdx.x * 256 + threadIdx.x;
    if (i < N_NODES) cnt[i] = 0;
}

__global__ __launch_bounds__(256) void k_count(const int* col, int* cnt) {
    int e = blockIdx.x * 256 + threadIdx.x;
    atomicAdd(&cnt[col[e]], 1);
}

__global__ __launch_bounds__(1024) void k_scan1(const int* cnt, int* offs, int* bsum) {
    __shared__ int s[1024];
    int tid = threadIdx.x;
    int gid = blockIdx.x * 1024 + tid;
    int v = (gid < N_NODES) ? cnt[gid] : 0;
    s[tid] = v;
    __syncthreads();
    for (int o = 1; o < 1024; o <<= 1) {
        int t = (tid >= o) ? s[tid - o] : 0;
        __syncthreads();
        s[tid] += t;
        __syncthreads();
    }
    if (gid < N_NODES) offs[gid] = s[tid] - v;
    if (tid == 1023) bsum[blockIdx.x] = s[1023];
}

__global__ __launch_bounds__(128) void k_scan2(int* bsum) {
    __shared__ int s[128];
    int tid = threadIdx.x;
    int v = (tid < 98) ? bsum[tid] : 0;
    s[tid] = v;
    __syncthreads();
    for (int o = 1; o < 128; o <<= 1) {
        int t = (tid >= o) ? s[tid - o] : 0;
        __syncthreads();
        s[tid] += t;
        __syncthreads();
    }
    if (tid < 98) bsum[tid] = s[tid] - v;
}

__global__ __launch_bounds__(1024) void k_scan3(int* offs, int* cur, const int* bsum) {
    int tid = threadIdx.x;
    int gid = blockIdx.x * 1024 + tid;
    if (gid < N_NODES) {
        int o = offs[gid] + bsum[blockIdx.x];
        offs[gid] = o;
        cur[gid] = o;
    }
    if (gid == 0) offs[N_NODES] = N_EDGES;
}

__global__ __launch_bounds__(256) void k_scatter(const int* row, const int* col,
                                                 const float* w, int* cur, int2* edata) {
    int e = blockIdx.x * 256 + threadIdx.x;
    int r = row[e];
    int c = col[e];
    int p = atomicAdd(&cur[c], 1);
    edata[p] = make_int2(r, __float_as_int(w[e]));
}

__global__ __launch_bounds__(256) void k_deg_dinv(const int* offs, const int2* edata,
                                                  float* dinv) {
    int tid = threadIdx.x;
    int lane = tid & 15;
    int node = blockIdx.x * 16 + (tid >> 4);
    int e0 = offs[node], e1 = offs[node + 1];
    float s = 0.0f;
    for (int e = e0 + lane; e < e1; e += 16)
        s += __int_as_float(edata[e].y);
    for (int o = 1; o < 16; o <<= 1) s += __shfl_xor(s, o, 64);
    if (lane == 0) dinv[node] = 1.0f / sqrtf(1.0f + s);
}

// =================== tier-3: edge-atomic fallback ===================

__global__ __launch_bounds__(256) void k_init_deg(float* deg) {
    int i = blockIdx.x * 256 + threadIdx.x;
    if (i < N_NODES) deg[i] = 1.0f;
}

__global__ __launch_bounds__(256) void k_deg_only(const int* col, const float* w, float* deg) {
    int e = blockIdx.x * 256 + threadIdx.x;
    atomicAdd(&deg[col[e]], w[e]);
}

__global__ __launch_bounds__(256) void k_dinv(float* deg) {
    int i = blockIdx.x * 256 + threadIdx.x;
    if (i < N_NODES) {
        float d = deg[i];
        deg[i] = (d > 0.0f) ? 1.0f / sqrtf(d) : 0.0f;
    }
}

__global__ __launch_bounds__(256) void k_self(const float* dinv, const float* h, float* agg) {
    int i = blockIdx.x * 256 + threadIdx.x;
    float d = dinv[i >> 4];
    agg[i] = d * d * h[i];
}

__global__ __launch_bounds__(256) void k_edge_atomic(const int* row, const int* col,
                                                     const float* w, const float* dinv,
                                                     const float* h, float* agg) {
    int gid = blockIdx.x * 256 + threadIdx.x;
    int e = gid >> 4, lane = gid & 15;
    int r = row[e], c = col[e];
    float nrm = dinv[r] * w[e] * dinv[c];
    atomicAdd(&agg[c * HID + lane], nrm * h[r * HID + lane]);
}

__global__ __launch_bounds__(256) void k_bias_relu_gemm2(const float* agg, const float* b1,
                                                         const float* W2, float* out2) {
    __shared__ float w2s[HID * HID];
    int tid = threadIdx.x;
    if (tid < HID * HID) w2s[tid] = W2[tid];
    __syncthreads();
    int lane = tid & 15;
    int node = blockIdx.x * 16 + (tid >> 4);
    float acc = fmaxf(agg[node * HID + lane] + b1[lane], 0.0f);
    int base = tid & 48;
    float h2 = 0.0f;
    for (int k = 0; k < HID; k++) {
        float v = __shfl(acc, base + k, 64);
        h2 += v * w2s[k * HID + lane];
    }
    out2[node * HID + lane] = h2;
}

__global__ __launch_bounds__(256) void k_final(const float* agg, const float* b2,
                                               const float* Wc, const float* bc, float* out) {
    __shared__ float wcs[HID * NCLS];
    __shared__ float bcs[NCLS];
    int tid = threadIdx.x;
    for (int i = tid; i < HID * NCLS; i += 256) wcs[i] = Wc[i];
    if (tid < NCLS) bcs[tid] = bc[tid];
    __syncthreads();
    int lane = tid & 15;
    int node = blockIdx.x * 16 + (tid >> 4);
    float acc = agg[node * HID + lane] + b2[lane];
    float l0 = bcs[lane];
    float l1 = bcs[lane + 16];
    float l2 = (lane < 8) ? bcs[lane + 32] : 0.0f;
    int base = tid & 48;
    for (int k = 0; k < HID; k++) {
        float v = __shfl(acc, base + k, 64);
        l0 += v * wcs[k * NCLS + lane];
        l1 += v * wcs[k * NCLS + lane + 16];
        if (lane < 8) l2 += v * wcs[k * NCLS + lane + 32];
    }
    float m = fmaxf(l0, l1);
    if (lane < 8) m = fmaxf(m, l2);
    for (int o = 1; o < 16; o <<= 1) m = fmaxf(m, __shfl_xor(m, o, 64));
    float s = expf(l0 - m) + expf(l1 - m) + ((lane < 8) ? expf(l2 - m) : 0.0f);
    for (int o = 1; o < 16; o <<= 1) s += __shfl_xor(s, o, 64);
    float ls = logf(s) + m;
    out[node * NCLS + lane] = l0 - ls;
    out[node * NCLS + lane + 16] = l1 - ls;
    if (lane < 8) out[node * NCLS + lane + 32] = l2 - ls;
}

extern "C" void kernel_launch(void* const* d_in, const int* in_sizes, int n_in,
                              void* d_out, int out_size, void* d_ws, size_t ws_size,
                              hipStream_t stream) {
    const float* z     = (const float*)d_in[0];
    const int*   eidx  = (const int*)d_in[1];
    const float* eattr = (const float*)d_in[2];
    const float* W1    = (const float*)d_in[3];
    const float* b1    = (const float*)d_in[4];
    const float* W2    = (const float*)d_in[5];
    const float* b2    = (const float*)d_in[6];
    const float* Wc    = (const float*)d_in[7];
    const float* bc    = (const float*)d_in[8];
    float* out = (float*)d_out;

    char* ws = (char*)d_ws;
    const int* rowp = eidx;
    const int* colp = eidx + N_EDGES;

    int nblk = (N_NODES + 255) / 256;               // 391
    int eblk = N_EDGES / 256;                       // 25000
    int sblk = (N_NODES + 1023) / 1024;             // 98
    int gblk = (N_NODES + 63) / 64;                 // 1563
    int ablk = N_NODES / 16;                        // 6250
    int fblk = (N_NODES * HID) / 256;               // 6250
    int exblk = (N_EDGES * HID) / 256;              // 400000

    if (ws_size >= (size_t)WS_T1_NEED) {
        // ---------- tier-1: atomic-free CSR build (wide fine sort) ----------
        int*   cbase  = (int*)(ws + OFF_CB);
        int*   tot    = (int*)(ws + OFF_TOT);
        float* dinv   = (float*)(ws + OFF_DINV);
        int*   offs   = (int*)(ws + OFF_OFFS);
        int*   histc  = (int*)(ws + OFF_HIST);      // overlays edata (time-disjoint)
        int*   histex = (int*)(ws + OFF_HISTEX);
        int*   cnt    = (int*)(ws + OFF_CNT);       // overlays dead histc region
        int2*  ebuf1  = (int2*)(ws + OFF_EBUF1);
        int2*  edat   = (int2*)(ws + OFF_EDATA);
        float* h1     = (float*)(ws + OFF_H1);
        float* hb     = (float*)(ws + OFF_HB);

        k_hist<<<B_PART, 1024, 0, stream>>>(colp, histc);
        k_colscan<<<K_BKT, 1024, 0, stream>>>(histc, histex, tot);
        k_basescan<<<1, 512, 0, stream>>>(tot, cbase);
        k_partition<<<B_PART, 1024, 0, stream>>>(rowp, colp, eattr, histc, histex, cbase, ebuf1);
        k_init2<<<nblk, 256, 0, stream>>>(cnt, dinv);
        k_bsA<<<K_BKT * 4, 1024, 0, stream>>>(ebuf1, cbase, cnt, dinv);
        k_bsOffs<<<K_BKT, 256, 0, stream>>>(cnt, cbase, offs, dinv);
        k_bsB<<<K_BKT * 2, 1024, 0, stream>>>(ebuf1, cbase, offs, edat);
        k_gemm1<<<gblk, 256, 0, stream>>>(z, W1, h1, dinv);      // h1 overlays dead ebuf1
        k_agg1<<<ablk, 256, 0, stream>>>(h1, dinv, offs, edat, b1, W2, hb);
        k_agg2<<<ablk, 256, 0, stream>>>(hb, dinv, offs, edat, b2, Wc, bc, out);
    } else if (ws_size >= (size_t)WS_T2_NEED) {
        // ---------- tier-2: atomic-CSR path (R5) ----------
        float* dinv = (float*)(ws + T2_DINV);
        int*   cnt  = (int*)(ws + T2_CNT);
        int*   offs = (int*)(ws + T2_OFFS);
        int2*  edat = (int2*)(ws + T2_EDATA);
        float* h1   = (float*)(ws + T2_H1);
        float* hb   = (float*)(ws + T2_HB);
        int*   bsum = (int*)(ws + T2_BSUM);

        k_init<<<nblk, 256, 0, stream>>>(cnt);
        k_count<<<eblk, 256, 0, stream>>>(colp, cnt);
        k_scan1<<<sblk, 1024, 0, stream>>>(cnt, offs, bsum);
        k_scan2<<<1, 128, 0, stream>>>(bsum);
        k_scan3<<<sblk, 1024, 0, stream>>>(offs, cnt, bsum);
        k_scatter<<<eblk, 256, 0, stream>>>(rowp, colp, eattr, cnt, edat);
        k_deg_dinv<<<ablk, 256, 0, stream>>>(offs, edat, dinv);
        k_gemm1<<<gblk, 256, 0, stream>>>(z, W1, h1, dinv);
        k_agg1<<<ablk, 256, 0, stream>>>(h1, dinv, offs, edat, b1, W2, hb);
        k_agg2<<<ablk, 256, 0, stream>>>(hb, dinv, offs, edat, b2, Wc, bc, out);
    } else {
        // ---------- tier-3: edge-atomic fallback ----------
        float* deg = (float*)(ws + OFF3_DEG);
        float* h1  = (float*)(ws + OFF3_H1);
        float* hb  = (float*)(ws + OFF3_HB);

        k_init_deg<<<nblk, 256, 0, stream>>>(deg);
        k_deg_only<<<eblk, 256, 0, stream>>>(colp, eattr, deg);
        k_dinv<<<nblk, 256, 0, stream>>>(deg);
        k_gemm1<<<gblk, 256, 0, stream>>>(z, W1, hb, nullptr);
        k_self<<<fblk, 256, 0, stream>>>(deg, hb, h1);
        k_edge_atomic<<<exblk, 256, 0, stream>>>(rowp, colp, eattr, deg, hb, h1);
        k_bias_relu_gemm2<<<ablk, 256, 0, stream>>>(h1, b1, W2, hb);
        k_self<<<fblk, 256, 0, stream>>>(deg, hb, h1);
        k_edge_atomic<<<exblk, 256, 0, stream>>>(rowp, colp, eattr, deg, hb, h1);
        k_final<<<ablk, 256, 0, stream>>>(h1, b2, Wc, bc, out);
    }
}

// Round 5
// 404.321 us; speedup vs baseline: 1.1021x; 1.1021x over previous
//
#include <hip/hip_runtime.h>
#include <hip/hip_bf16.h>
#include <hip/hip_fp16.h>

// GCN inference: conv1(128->16)+ReLU -> conv2(16->16) -> linear(16->40) -> log_softmax
// R12 post-mortem: wide fine-sort REGRESSED (430->445; bsA/bsB re-read ebuf1
// and pay global atomics -- pass-splitting doubles traffic). Reverted to R11
// bucketsort. R12's profile exposed k_agg2: 79us, FETCH 225MB = edata 51MB +
// ~174MB hb-gather misses: hb (6.4MB f32) thrashes each XCD's 4MiB private L2
// under random row gathers. R13: store h1/hb as fp16 (3.2MB) -> whole table
// fits per-XCD L2, gathers become L2 hits and transactions halve. gemm1
// converts on store; tier-3 keeps f32 variant (k_gemm1f).

#define N_NODES 100000
#define N_EDGES 6400000
#define IN_DIM  128
#define HID     16
#define NCLS    40

#define K_BKT    391         // buckets = col>>8, 256 nodes each (last: 160)
#define BKT_SH   8
#define BKT_NB   256         // nodes per bucket
#define BKT_MASK 255
#define B_PART   1000        // histogram/partition blocks
#define CHUNK    6400        // edges per partition block (fits LDS staging)

// ---- tier-1 workspace layout (bytes) ----
#define OFF_CB    0          // int[392] bucket bases (exclusive scan of totals)
#define OFF_TOT   1600       // int[391] bucket totals
#define OFF_DINV  3200       // float[N]
#define OFF_OFFS  403200     // int[N+1]
#define OFF_EBUF1 803328     // int2[E] bucket-major edges (dead after bucketsort)
#define OFF_EDATA 52003328   // int2[E] final CSR (row, w)
#define OFF_HIST   OFF_EDATA               // int[1000*391] counts (dead before bucketsort)
#define OFF_HISTEX (OFF_EDATA + 1568000)   // int[1000*391] exclusive scans
#define WS_T1_NEED 103600000
// h1/hb (fp16, N*16*2 = 3.2MB each) overlay the dead ebuf1 region:
#define OFF_H1    OFF_EBUF1              // __half[N*16]
#define OFF_HB    (OFF_EBUF1 + 6400000)  // __half[N*16]

// ---- tier-2 workspace layout (R5 atomic-CSR path) ----
#define T2_DINV  0
#define T2_CNT   400128
#define T2_OFFS  800256
#define T2_EDATA 1200384
#define T2_H1    52400384
#define T2_HB    58800384
#define T2_BSUM  65200384
#define WS_T2_NEED 65210000

// ---- tier-3 fallback layout ----
#define OFF3_DEG 0
#define OFF3_H1  400128
#define OFF3_HB  6800384

// =================== tier-1: deterministic CSR build ===================

__global__ __launch_bounds__(1024) void k_hist(const int* col, int* histcnt) {
    __shared__ int h[K_BKT];
    int t = threadIdx.x;
    if (t < K_BKT) h[t] = 0;
    __syncthreads();
    int b = blockIdx.x;
    int end = (b + 1) * CHUNK;
    int e = b * CHUNK + t;
    for (; e + 3072 < end; e += 4096) {
        int c0 = col[e];
        int c1 = col[e + 1024];
        int c2 = col[e + 2048];
        int c3 = col[e + 3072];
        atomicAdd(&h[c0 >> BKT_SH], 1);               // LDS int atomic: fast path
        atomicAdd(&h[c1 >> BKT_SH], 1);
        atomicAdd(&h[c2 >> BKT_SH], 1);
        atomicAdd(&h[c3 >> BKT_SH], 1);
    }
    for (; e < end; e += 1024)
        atomicAdd(&h[col[e] >> BKT_SH], 1);
    __syncthreads();
    if (t < K_BKT) histcnt[b * K_BKT + t] = h[t];
}

// one block per bucket k: exclusive-scan histcnt[.][k] over the 1000 blocks
// into histex (histcnt preserved -- partition needs local counts).
__global__ __launch_bounds__(1024) void k_colscan(const int* histcnt, int* histex, int* tot) {
    __shared__ int s[1024];
    int t = threadIdx.x;
    int k = blockIdx.x;
    int v = (t < B_PART) ? histcnt[t * K_BKT + k] : 0;
    s[t] = v;
    __syncthreads();
    for (int o = 1; o < 1024; o <<= 1) {
        int a = (t >= o) ? s[t - o] : 0;
        __syncthreads();
        s[t] += a;
        __syncthreads();
    }
    if (t < B_PART) histex[t * K_BKT + k] = s[t] - v;  // exclusive
    if (t == 0) tot[k] = s[B_PART - 1];                // inclusive total
}

__global__ __launch_bounds__(512) void k_basescan(const int* tot, int* cbase) {
    __shared__ int s[512];
    int t = threadIdx.x;
    int v = (t < K_BKT) ? tot[t] : 0;
    s[t] = v;
    __syncthreads();
    for (int o = 1; o < 512; o <<= 1) {
        int a = (t >= o) ? s[t - o] : 0;
        __syncthreads();
        s[t] += a;
        __syncthreads();
    }
    if (t < K_BKT) cbase[t] = s[t] - v;               // exclusive
    if (t == 0) cbase[K_BKT] = N_EDGES;
}

// LDS-staged partition: counting-sort the block's chunk in LDS, then write
// bucket-segments to global in slot order (coalesced runs).
// packed = row | (col_local<<17)
__global__ __launch_bounds__(1024) void k_partition(const int* row, const int* col,
                                                    const float* w, const int* histcnt,
                                                    const int* histex, const int* cbase,
                                                    int2* ebuf1) {
    __shared__ int2 led[CHUNK];          // 51.2KB staged edges (local sorted order)
    __shared__ int  sscan[1024];
    __shared__ int  lbase[K_BKT + 1];    // local exclusive offsets
    __shared__ int  gofs[K_BKT];         // global_base - local_base per bucket
    __shared__ int  cur[K_BKT];
    int t = threadIdx.x;
    int b = blockIdx.x;
    // local exclusive scan of this block's bucket counts
    int v = (t < K_BKT) ? histcnt[b * K_BKT + t] : 0;
    sscan[t] = v;
    __syncthreads();
    for (int o = 1; o < 1024; o <<= 1) {
        int a = (t >= o) ? sscan[t - o] : 0;
        __syncthreads();
        sscan[t] += a;
        __syncthreads();
    }
    if (t < K_BKT) {
        int ex = sscan[t] - v;
        lbase[t] = ex;
        cur[t] = ex;
        gofs[t] = cbase[t] + histex[b * K_BKT + t] - ex;
    }
    if (t == 0) lbase[K_BKT] = CHUNK;
    __syncthreads();
    // local scatter into LDS (2x unrolled; LDS store latency trivial)
    int end = (b + 1) * CHUNK;
    int e = b * CHUNK + t;
    for (; e + 1024 < end; e += 2048) {
        int c0 = col[e],  c1 = col[e + 1024];
        int r0 = row[e],  r1 = row[e + 1024];
        float w0 = w[e],  w1 = w[e + 1024];
        int p0 = atomicAdd(&cur[c0 >> BKT_SH], 1);
        int p1 = atomicAdd(&cur[c1 >> BKT_SH], 1);
        led[p0] = make_int2(r0 | ((c0 & BKT_MASK) << 17), __float_as_int(w0));
        led[p1] = make_int2(r1 | ((c1 & BKT_MASK) << 17), __float_as_int(w1));
    }
    for (; e < end; e += 1024) {
        int c = col[e];
        int p = atomicAdd(&cur[c >> BKT_SH], 1);
        led[p] = make_int2(row[e] | ((c & BKT_MASK) << 17), __float_as_int(w[e]));
    }
    __syncthreads();
    // write-out in slot order -> consecutive threads hit consecutive global
    // addresses within each bucket segment (coalesced runs, no atomic dep).
    for (int i = t; i < CHUNK; i += 1024) {
        int2 ed = led[i];
        int lo = 0, hi = K_BKT;          // find k: lbase[k] <= i < lbase[k+1]
        while (hi - lo > 1) {
            int mid = (lo + hi) >> 1;
            if (lbase[mid] <= i) lo = mid; else hi = mid;
        }
        ebuf1[gofs[lo] + i] = ed;
    }
}

// per-bucket: fine counting sort (256 local nodes) -> edata CSR; also offs + dinv.
__global__ __launch_bounds__(1024) void k_bucketsort(const int2* ebuf1, const int* cbase,
                                                     int2* edata, int* offs, float* dinv) {
    __shared__ int   cnt[BKT_NB];
    __shared__ float degw[BKT_NB];
    __shared__ int   sc[BKT_NB];
    __shared__ int   cur[BKT_NB];
    int t = threadIdx.x;
    int k = blockIdx.x;
    if (t < BKT_NB) { cnt[t] = 0; degw[t] = 0.0f; }
    __syncthreads();
    int e0 = cbase[k], e1 = cbase[k + 1];
    // pass A: local histogram + weighted degree (4x unrolled for MLP)
    int e = e0 + t;
    for (; e + 3072 < e1; e += 4096) {
        int2 v0 = ebuf1[e];
        int2 v1 = ebuf1[e + 1024];
        int2 v2 = ebuf1[e + 2048];
        int2 v3 = ebuf1[e + 3072];
        int a0 = v0.x >> 17, a1 = v1.x >> 17, a2 = v2.x >> 17, a3 = v3.x >> 17;
        atomicAdd(&cnt[a0], 1); atomicAdd(&degw[a0], __int_as_float(v0.y));
        atomicAdd(&cnt[a1], 1); atomicAdd(&degw[a1], __int_as_float(v1.y));
        atomicAdd(&cnt[a2], 1); atomicAdd(&degw[a2], __int_as_float(v2.y));
        atomicAdd(&cnt[a3], 1); atomicAdd(&degw[a3], __int_as_float(v3.y));
    }
    for (; e < e1; e += 1024) {
        int2 v = ebuf1[e];
        int cl = v.x >> 17;
        atomicAdd(&cnt[cl], 1);
        atomicAdd(&degw[cl], __int_as_float(v.y));
    }
    __syncthreads();
    int c0 = (t < BKT_NB) ? cnt[t] : 0;
    if (t < BKT_NB) sc[t] = c0;
    __syncthreads();
    for (int o = 1; o < BKT_NB; o <<= 1) {            // inclusive scan of 256
        int a = (t < BKT_NB && t >= o) ? sc[t - o] : 0;
        __syncthreads();
        if (t < BKT_NB) sc[t] += a;
        __syncthreads();
    }
    // exclusive offsets; emit offs + dinv for this bucket's nodes
    if (t < BKT_NB) {
        int ex = sc[t] - c0;
        cur[t] = e0 + ex;
        int node = k * BKT_NB + t;
        if (node < N_NODES) {
            offs[node] = e0 + ex;
            dinv[node] = rsqrtf(1.0f + degw[t]);
        }
    }
    if (k == 0 && t == 0) offs[N_NODES] = N_EDGES;
    __syncthreads();
    // pass B: scatter (L2-local window), 4x unrolled
    e = e0 + t;
    for (; e + 3072 < e1; e += 4096) {
        int2 v0 = ebuf1[e];
        int2 v1 = ebuf1[e + 1024];
        int2 v2 = ebuf1[e + 2048];
        int2 v3 = ebuf1[e + 3072];
        int p0 = atomicAdd(&cur[v0.x >> 17], 1);      // LDS atomic
        int p1 = atomicAdd(&cur[v1.x >> 17], 1);
        int p2 = atomicAdd(&cur[v2.x >> 17], 1);
        int p3 = atomicAdd(&cur[v3.x >> 17], 1);
        edata[p0] = make_int2(v0.x & 131071, v0.y);
        edata[p1] = make_int2(v1.x & 131071, v1.y);
        edata[p2] = make_int2(v2.x & 131071, v2.y);
        edata[p3] = make_int2(v3.x & 131071, v3.y);
    }
    for (; e < e1; e += 1024) {
        int2 v = ebuf1[e];
        int p = atomicAdd(&cur[v.x >> 17], 1);
        edata[p] = make_int2(v.x & 131071, v.y);
    }
}

// =================== shared compute kernels ===================

// h1 = fp16(dinv[node] * (z @ W1))  -- fp16 storage so the gather table
// (3.2MB) fits each XCD's 4MiB L2.
__global__ __launch_bounds__(256) void k_gemm1(const float* z, const float* W1,
                                               __half* h1, const float* dinv) {
    __shared__ float w1s[IN_DIM * HID];
    __shared__ float zs[64 * 132];
    int tid = threadIdx.x;
    for (int i = tid; i < IN_DIM * HID / 4; i += 256)
        ((float4*)w1s)[i] = ((const float4*)W1)[i];
    int nodeBase = blockIdx.x * 64;
    for (int i = tid; i < 64 * 32; i += 256) {
        int nl = i >> 5, kq = i & 31;
        int node = nodeBase + nl;
        float4 v = (node < N_NODES) ? ((const float4*)z)[node * 32 + kq]
                                    : make_float4(0.f, 0.f, 0.f, 0.f);
        *(float4*)&zs[nl * 132 + kq * 4] = v;
    }
    __syncthreads();
    int nl = tid >> 2;
    int jb = (tid & 3) * 4;
    int node = nodeBase + nl;
    float4 acc = make_float4(0.f, 0.f, 0.f, 0.f);
    for (int k = 0; k < IN_DIM; k++) {
        float s = zs[nl * 132 + k];
        float4 wv = *(const float4*)&w1s[k * HID + jb];
        acc.x += s * wv.x; acc.y += s * wv.y; acc.z += s * wv.z; acc.w += s * wv.w;
    }
    if (node < N_NODES) {
        float dv = dinv ? dinv[node] : 1.0f;
        union { __half2 h2[2]; uint2 u; } pk;
        pk.h2[0] = __floats2half2_rn(acc.x * dv, acc.y * dv);
        pk.h2[1] = __floats2half2_rn(acc.z * dv, acc.w * dv);
        ((uint2*)h1)[node * 4 + (tid & 3)] = pk.u;    // 8B store: 4 halves
    }
}

// f32-output variant for tier-3 (edge-atomic path keeps float buffers)
__global__ __launch_bounds__(256) void k_gemm1f(const float* z, const float* W1, float* h1,
                                                const float* dinv) {
    __shared__ float w1s[IN_DIM * HID];
    __shared__ float zs[64 * 132];
    int tid = threadIdx.x;
    for (int i = tid; i < IN_DIM * HID / 4; i += 256)
        ((float4*)w1s)[i] = ((const float4*)W1)[i];
    int nodeBase = blockIdx.x * 64;
    for (int i = tid; i < 64 * 32; i += 256) {
        int nl = i >> 5, kq = i & 31;
        int node = nodeBase + nl;
        float4 v = (node < N_NODES) ? ((const float4*)z)[node * 32 + kq]
                                    : make_float4(0.f, 0.f, 0.f, 0.f);
        *(float4*)&zs[nl * 132 + kq * 4] = v;
    }
    __syncthreads();
    int nl = tid >> 2;
    int jb = (tid & 3) * 4;
    int node = nodeBase + nl;
    float4 acc = make_float4(0.f, 0.f, 0.f, 0.f);
    for (int k = 0; k < IN_DIM; k++) {
        float s = zs[nl * 132 + k];
        float4 wv = *(const float4*)&w1s[k * HID + jb];
        acc.x += s * wv.x; acc.y += s * wv.y; acc.z += s * wv.z; acc.w += s * wv.w;
    }
    if (node < N_NODES) {
        float dv = dinv ? dinv[node] : 1.0f;
        acc.x *= dv; acc.y *= dv; acc.z *= dv; acc.w *= dv;
        ((float4*)h1)[node * 4 + (tid & 3)] = acc;
    }
}

// 8x-unrolled CSR edge aggregation over fp16 feature table: 8 independent
// edata loads + 8 independent 2B gathers in flight per 16-lane group.
__device__ __forceinline__ float edge_agg(const __half* __restrict__ h,
                                          const int2* __restrict__ edata,
                                          int e0, int e1, int lane, float acc) {
    int e = e0;
    for (; e + 8 <= e1; e += 8) {
        int2 d0 = edata[e];
        int2 d1 = edata[e + 1];
        int2 d2 = edata[e + 2];
        int2 d3 = edata[e + 3];
        int2 d4 = edata[e + 4];
        int2 d5 = edata[e + 5];
        int2 d6 = edata[e + 6];
        int2 d7 = edata[e + 7];
        float g0 = __half2float(h[d0.x * HID + lane]);
        float g1 = __half2float(h[d1.x * HID + lane]);
        float g2 = __half2float(h[d2.x * HID + lane]);
        float g3 = __half2float(h[d3.x * HID + lane]);
        float g4 = __half2float(h[d4.x * HID + lane]);
        float g5 = __half2float(h[d5.x * HID + lane]);
        float g6 = __half2float(h[d6.x * HID + lane]);
        float g7 = __half2float(h[d7.x * HID + lane]);
        acc += __int_as_float(d0.y) * g0;
        acc += __int_as_float(d1.y) * g1;
        acc += __int_as_float(d2.y) * g2;
        acc += __int_as_float(d3.y) * g3;
        acc += __int_as_float(d4.y) * g4;
        acc += __int_as_float(d5.y) * g5;
        acc += __int_as_float(d6.y) * g6;
        acc += __int_as_float(d7.y) * g7;
    }
    for (; e < e1; e++) {
        int2 ed = edata[e];
        acc += __int_as_float(ed.y) * __half2float(h[ed.x * HID + lane]);
    }
    return acc;
}

// conv1 aggregate (+b1, ReLU), fused h2 = x1 @ W2; hb = fp16(dinv * h2)
__global__ __launch_bounds__(256) void k_agg1(const __half* h1, const float* dinv,
                                              const int* offs, const int2* edata,
                                              const float* b1, const float* W2, __half* hb) {
    __shared__ float w2s[HID * HID];
    int tid = threadIdx.x;
    if (tid < HID * HID) w2s[tid] = W2[tid];
    __syncthreads();
    int lane = tid & 15;
    int node = blockIdx.x * 16 + (tid >> 4);
    int e0 = offs[node], e1 = offs[node + 1];
    float self = __half2float(h1[node * HID + lane]);
    float acc = edge_agg(h1, edata, e0, e1, lane, self);
    float d = dinv[node];
    acc = d * acc + b1[lane];
    acc = fmaxf(acc, 0.0f);
    int base = tid & 48;
    float h2 = 0.0f;
    for (int k = 0; k < HID; k++) {
        float v = __shfl(acc, base + k, 64);
        h2 += v * w2s[k * HID + lane];
    }
    hb[node * HID + lane] = __float2half(d * h2);
}

// conv2 aggregate (+b2), classifier (16->40) + log_softmax
__global__ __launch_bounds__(256) void k_agg2(const __half* hb, const float* dinv,
                                              const int* offs, const int2* edata,
                                              const float* b2, const float* Wc,
                                              const float* bc, float* out) {
    __shared__ float wcs[HID * NCLS];
    __shared__ float bcs[NCLS];
    int tid = threadIdx.x;
    for (int i = tid; i < HID * NCLS; i += 256) wcs[i] = Wc[i];
    if (tid < NCLS) bcs[tid] = bc[tid];
    __syncthreads();
    int lane = tid & 15;
    int node = blockIdx.x * 16 + (tid >> 4);
    int e0 = offs[node], e1 = offs[node + 1];
    float self = __half2float(hb[node * HID + lane]);
    float acc = edge_agg(hb, edata, e0, e1, lane, self);
    acc = dinv[node] * acc + b2[lane];
    float l0 = bcs[lane];
    float l1 = bcs[lane + 16];
    float l2 = (lane < 8) ? bcs[lane + 32] : 0.0f;
    int base = tid & 48;
    for (int k = 0; k < HID; k++) {
        float v = __shfl(acc, base + k, 64);
        l0 += v * wcs[k * NCLS + lane];
        l1 += v * wcs[k * NCLS + lane + 16];
        if (lane < 8) l2 += v * wcs[k * NCLS + lane + 32];
    }
    float m = fmaxf(l0, l1);
    if (lane < 8) m = fmaxf(m, l2);
    for (int o = 1; o < 16; o <<= 1) m = fmaxf(m, __shfl_xor(m, o, 64));
    float s = expf(l0 - m) + expf(l1 - m) + ((lane < 8) ? expf(l2 - m) : 0.0f);
    for (int o = 1; o < 16; o <<= 1) s += __shfl_xor(s, o, 64);
    float ls = logf(s) + m;
    out[node * NCLS + lane] = l0 - ls;
    out[node * NCLS + lane + 16] = l1 - ls;
    if (lane < 8) out[node * NCLS + lane + 32] = l2 - ls;
}

// =================== tier-2: R5 atomic-CSR build ===================

__global__ __launch_bounds__(256) void k_init(int* cnt) {
    int i = blockIdx.x * 256 + threadIdx.x;
    if (i < N_NODES) cnt[i] = 0;
}

__global__ __launch_bounds__(256) void k_count(const int* col, int* cnt) {
    int e = blockIdx.x * 256 + threadIdx.x;
    atomicAdd(&cnt[col[e]], 1);
}

__global__ __launch_bounds__(1024) void k_scan1(const int* cnt, int* offs, int* bsum) {
    __shared__ int s[1024];
    int tid = threadIdx.x;
    int gid = blockIdx.x * 1024 + tid;
    int v = (gid < N_NODES) ? cnt[gid] : 0;
    s[tid] = v;
    __syncthreads();
    for (int o = 1; o < 1024; o <<= 1) {
        int t = (tid >= o) ? s[tid - o] : 0;
        __syncthreads();
        s[tid] += t;
        __syncthreads();
    }
    if (gid < N_NODES) offs[gid] = s[tid] - v;
    if (tid == 1023) bsum[blockIdx.x] = s[1023];
}

__global__ __launch_bounds__(128) void k_scan2(int* bsum) {
    __shared__ int s[128];
    int tid = threadIdx.x;
    int v = (tid < 98) ? bsum[tid] : 0;
    s[tid] = v;
    __syncthreads();
    for (int o = 1; o < 128; o <<= 1) {
        int t = (tid >= o) ? s[tid - o] : 0;
        __syncthreads();
        s[tid] += t;
        __syncthreads();
    }
    if (tid < 98) bsum[tid] = s[tid] - v;
}

__global__ __launch_bounds__(1024) void k_scan3(int* offs, int* cur, const int* bsum) {
    int tid = threadIdx.x;
    int gid = blockIdx.x * 1024 + tid;
    if (gid < N_NODES) {
        int o = offs[gid] + bsum[blockIdx.x];
        offs[gid] = o;
        cur[gid] = o;
    }
    if (gid == 0) offs[N_NODES] = N_EDGES;
}

__global__ __launch_bounds__(256) void k_scatter(const int* row, const int* col,
                                                 const float* w, int* cur, int2* edata) {
    int e = blockIdx.x * 256 + threadIdx.x;
    int r = row[e];
    int c = col[e];
    int p = atomicAdd(&cur[c], 1);
    edata[p] = make_int2(r, __float_as_int(w[e]));
}

__global__ __launch_bounds__(256) void k_deg_dinv(const int* offs, const int2* edata,
                                                  float* dinv) {
    int tid = threadIdx.x;
    int lane = tid & 15;
    int node = blockIdx.x * 16 + (tid >> 4);
    int e0 = offs[node], e1 = offs[node + 1];
    float s = 0.0f;
    for (int e = e0 + lane; e < e1; e += 16)
        s += __int_as_float(edata[e].y);
    for (int o = 1; o < 16; o <<= 1) s += __shfl_xor(s, o, 64);
    if (lane == 0) dinv[node] = 1.0f / sqrtf(1.0f + s);
}

// =================== tier-3: edge-atomic fallback ===================

__global__ __launch_bounds__(256) void k_init_deg(float* deg) {
    int i = blockIdx.x * 256 + threadIdx.x;
    if (i < N_NODES) deg[i] = 1.0f;
}

__global__ __launch_bounds__(256) void k_deg_only(const int* col, const float* w, float* deg) {
    int e = blockIdx.x * 256 + threadIdx.x;
    atomicAdd(&deg[col[e]], w[e]);
}

__global__ __launch_bounds__(256) void k_dinv(float* deg) {
    int i = blockIdx.x * 256 + threadIdx.x;
    if (i < N_NODES) {
        float d = deg[i];
        deg[i] = (d > 0.0f) ? 1.0f / sqrtf(d) : 0.0f;
    }
}

__global__ __launch_bounds__(256) void k_self(const float* dinv, const float* h, float* agg) {
    int i = blockIdx.x * 256 + threadIdx.x;
    float d = dinv[i >> 4];
    agg[i] = d * d * h[i];
}

__global__ __launch_bounds__(256) void k_edge_atomic(const int* row, const int* col,
                                                     const float* w, const float* dinv,
                                                     const float* h, float* agg) {
    int gid = blockIdx.x * 256 + threadIdx.x;
    int e = gid >> 4, lane = gid & 15;
    int r = row[e], c = col[e];
    float nrm = dinv[r] * w[e] * dinv[c];
    atomicAdd(&agg[c * HID + lane], nrm * h[r * HID + lane]);
}

__global__ __launch_bounds__(256) void k_bias_relu_gemm2(const float* agg, const float* b1,
                                                         const float* W2, float* out2) {
    __shared__ float w2s[HID * HID];
    int tid = threadIdx.x;
    if (tid < HID * HID) w2s[tid] = W2[tid];
    __syncthreads();
    int lane = tid & 15;
    int node = blockIdx.x * 16 + (tid >> 4);
    float acc = fmaxf(agg[node * HID + lane] + b1[lane], 0.0f);
    int base = tid & 48;
    float h2 = 0.0f;
    for (int k = 0; k < HID; k++) {
        float v = __shfl(acc, base + k, 64);
        h2 += v * w2s[k * HID + lane];
    }
    out2[node * HID + lane] = h2;
}

__global__ __launch_bounds__(256) void k_final(const float* agg, const float* b2,
                                               const float* Wc, const float* bc, float* out) {
    __shared__ float wcs[HID * NCLS];
    __shared__ float bcs[NCLS];
    int tid = threadIdx.x;
    for (int i = tid; i < HID * NCLS; i += 256) wcs[i] = Wc[i];
    if (tid < NCLS) bcs[tid] = bc[tid];
    __syncthreads();
    int lane = tid & 15;
    int node = blockIdx.x * 16 + (tid >> 4);
    float acc = agg[node * HID + lane] + b2[lane];
    float l0 = bcs[lane];
    float l1 = bcs[lane + 16];
    float l2 = (lane < 8) ? bcs[lane + 32] : 0.0f;
    int base = tid & 48;
    for (int k = 0; k < HID; k++) {
        float v = __shfl(acc, base + k, 64);
        l0 += v * wcs[k * NCLS + lane];
        l1 += v * wcs[k * NCLS + lane + 16];
        if (lane < 8) l2 += v * wcs[k * NCLS + lane + 32];
    }
    float m = fmaxf(l0, l1);
    if (lane < 8) m = fmaxf(m, l2);
    for (int o = 1; o < 16; o <<= 1) m = fmaxf(m, __shfl_xor(m, o, 64));
    float s = expf(l0 - m) + expf(l1 - m) + ((lane < 8) ? expf(l2 - m) : 0.0f);
    for (int o = 1; o < 16; o <<= 1) s += __shfl_xor(s, o, 64);
    float ls = logf(s) + m;
    out[node * NCLS + lane] = l0 - ls;
    out[node * NCLS + lane + 16] = l1 - ls;
    if (lane < 8) out[node * NCLS + lane + 32] = l2 - ls;
}

extern "C" void kernel_launch(void* const* d_in, const int* in_sizes, int n_in,
                              void* d_out, int out_size, void* d_ws, size_t ws_size,
                              hipStream_t stream) {
    const float* z     = (const float*)d_in[0];
    const int*   eidx  = (const int*)d_in[1];
    const float* eattr = (const float*)d_in[2];
    const float* W1    = (const float*)d_in[3];
    const float* b1    = (const float*)d_in[4];
    const float* W2    = (const float*)d_in[5];
    const float* b2    = (const float*)d_in[6];
    const float* Wc    = (const float*)d_in[7];
    const float* bc    = (const float*)d_in[8];
    float* out = (float*)d_out;

    char* ws = (char*)d_ws;
    const int* rowp = eidx;
    const int* colp = eidx + N_EDGES;

    int nblk = (N_NODES + 255) / 256;               // 391
    int eblk = N_EDGES / 256;                       // 25000
    int sblk = (N_NODES + 1023) / 1024;             // 98
    int gblk = (N_NODES + 63) / 64;                 // 1563
    int ablk = N_NODES / 16;                        // 6250
    int fblk = (N_NODES * HID) / 256;               // 6250
    int exblk = (N_EDGES * HID) / 256;              // 400000

    if (ws_size >= (size_t)WS_T1_NEED) {
        // ---------- tier-1: atomic-free CSR build + fp16 gather tables ----------
        int*    cbase  = (int*)(ws + OFF_CB);
        int*    tot    = (int*)(ws + OFF_TOT);
        float*  dinv   = (float*)(ws + OFF_DINV);
        int*    offs   = (int*)(ws + OFF_OFFS);
        int*    histc  = (int*)(ws + OFF_HIST);     // overlays edata (time-disjoint)
        int*    histex = (int*)(ws + OFF_HISTEX);
        int2*   ebuf1  = (int2*)(ws + OFF_EBUF1);
        int2*   edat   = (int2*)(ws + OFF_EDATA);
        __half* h1     = (__half*)(ws + OFF_H1);
        __half* hb     = (__half*)(ws + OFF_HB);

        k_hist<<<B_PART, 1024, 0, stream>>>(colp, histc);
        k_colscan<<<K_BKT, 1024, 0, stream>>>(histc, histex, tot);
        k_basescan<<<1, 512, 0, stream>>>(tot, cbase);
        k_partition<<<B_PART, 1024, 0, stream>>>(rowp, colp, eattr, histc, histex, cbase, ebuf1);
        k_bucketsort<<<K_BKT, 1024, 0, stream>>>(ebuf1, cbase, edat, offs, dinv);
        k_gemm1<<<gblk, 256, 0, stream>>>(z, W1, h1, dinv);      // h1 overlays dead ebuf1
        k_agg1<<<ablk, 256, 0, stream>>>(h1, dinv, offs, edat, b1, W2, hb);
        k_agg2<<<ablk, 256, 0, stream>>>(hb, dinv, offs, edat, b2, Wc, bc, out);
    } else if (ws_size >= (size_t)WS_T2_NEED) {
        // ---------- tier-2: atomic-CSR path (R5) ----------
        float*  dinv = (float*)(ws + T2_DINV);
        int*    cnt  = (int*)(ws + T2_CNT);
        int*    offs = (int*)(ws + T2_OFFS);
        int2*   edat = (int2*)(ws + T2_EDATA);
        __half* h1   = (__half*)(ws + T2_H1);
        __half* hb   = (__half*)(ws + T2_HB);
        int*    bsum = (int*)(ws + T2_BSUM);

        k_init<<<nblk, 256, 0, stream>>>(cnt);
        k_count<<<eblk, 256, 0, stream>>>(colp, cnt);
        k_scan1<<<sblk, 1024, 0, stream>>>(cnt, offs, bsum);
        k_scan2<<<1, 128, 0, stream>>>(bsum);
        k_scan3<<<sblk, 1024, 0, stream>>>(offs, cnt, bsum);
        k_scatter<<<eblk, 256, 0, stream>>>(rowp, colp, eattr, cnt, edat);
        k_deg_dinv<<<ablk, 256, 0, stream>>>(offs, edat, dinv);
        k_gemm1<<<gblk, 256, 0, stream>>>(z, W1, h1, dinv);
        k_agg1<<<ablk, 256, 0, stream>>>(h1, dinv, offs, edat, b1, W2, hb);
        k_agg2<<<ablk, 256, 0, stream>>>(hb, dinv, offs, edat, b2, Wc, bc, out);
    } else {
        // ---------- tier-3: edge-atomic fallback (f32 throughout) ----------
        float* deg = (float*)(ws + OFF3_DEG);
        float* h1  = (float*)(ws + OFF3_H1);
        float* hb  = (float*)(ws + OFF3_HB);

        k_init_deg<<<nblk, 256, 0, stream>>>(deg);
        k_deg_only<<<eblk, 256, 0, stream>>>(colp, eattr, deg);
        k_dinv<<<nblk, 256, 0, stream>>>(deg);
        k_gemm1f<<<gblk, 256, 0, stream>>>(z, W1, hb, nullptr);
        k_self<<<fblk, 256, 0, stream>>>(deg, hb, h1);
        k_edge_atomic<<<exblk, 256, 0, stream>>>(rowp, colp, eattr, deg, hb, h1);
        k_bias_relu_gemm2<<<ablk, 256, 0, stream>>>(h1, b1, W2, hb);
        k_self<<<fblk, 256, 0, stream>>>(deg, hb, h1);
        k_edge_atomic<<<exblk, 256, 0, stream>>>(rowp, colp, eattr, deg, hb, h1);
        k_final<<<ablk, 256, 0, stream>>>(h1, b2, Wc, bc, out);
    }
}